// Round 1
// baseline (1281.812 us; speedup 1.0000x reference)
//
#include <hip/hip_runtime.h>

#define WAVES_PER_BLOCK 4
#define NBLOCKS 2048
#define NEG_BIG (-3.0e38f)

// One wave (64 lanes) per row. C <= 1024 (here C=1000 -> 250 float4).
// Row held entirely in registers: 4 float4 per lane. Single global read.
__global__ __launch_bounds__(256, 8) void focal_rows(
    const float* __restrict__ input,
    const int* __restrict__ target,
    float* __restrict__ partials,
    int N, int C)
{
    const int lane = threadIdx.x & 63;
    const int wave = threadIdx.x >> 6;
    const int gwave = blockIdx.x * WAVES_PER_BLOCK + wave;
    const int wavesTotal = gridDim.x * WAVES_PER_BLOCK;
    const int nf4 = C >> 2;   // 250 for C=1000 (C divisible by 4)

    float acc = 0.0f;

    for (int row = gwave; row < N; row += wavesTotal) {
        const float* rp = input + (size_t)row * (size_t)C;
        const float4* rp4 = (const float4*)rp;

        float4 v[4];
#pragma unroll
        for (int i = 0; i < 4; ++i) {
            const int f = i * 64 + lane;
            if (f < nf4) {
                v[i] = rp4[f];
            } else {
                v[i] = make_float4(NEG_BIG, NEG_BIG, NEG_BIG, NEG_BIG);
            }
        }
        // target class logit (broadcast load; row is L1-hot)
        const int t = target[row];
        const float xt = rp[t];

        // row max
        float m = NEG_BIG;
#pragma unroll
        for (int i = 0; i < 4; ++i) {
            m = fmaxf(m, fmaxf(fmaxf(v[i].x, v[i].y), fmaxf(v[i].z, v[i].w)));
        }
#pragma unroll
        for (int off = 32; off >= 1; off >>= 1)
            m = fmaxf(m, __shfl_xor(m, off, 64));

        // sum exp(x - m); masked entries (NEG_BIG - m) underflow exp -> 0
        float s = 0.0f;
#pragma unroll
        for (int i = 0; i < 4; ++i) {
            s += __expf(v[i].x - m);
            s += __expf(v[i].y - m);
            s += __expf(v[i].z - m);
            s += __expf(v[i].w - m);
        }
#pragma unroll
        for (int off = 32; off >= 1; off >>= 1)
            s += __shfl_xor(s, off, 64);

        const float logsum = m + __logf(s);
        const float logpt  = xt - logsum;
        const float pt     = __expf(logpt);
        const float w      = (t > 0) ? 0.25f : 0.75f;   // ALPHA / 1-ALPHA
        const float omp    = 1.0f - pt;
        const float loss   = -(omp * omp) * (logpt * w); // GAMMA = 2

        acc += loss;   // identical value in all 64 lanes
    }

    __shared__ float sacc[WAVES_PER_BLOCK];
    if (lane == 0) sacc[wave] = acc;
    __syncthreads();
    if (threadIdx.x == 0) {
        float b = 0.0f;
#pragma unroll
        for (int i = 0; i < WAVES_PER_BLOCK; ++i) b += sacc[i];
        partials[blockIdx.x] = b;
    }
}

__global__ __launch_bounds__(256) void reduce_partials(
    const float* __restrict__ partials, int nb,
    float* __restrict__ out, float invN)
{
    float s = 0.0f;
    for (int i = threadIdx.x; i < nb; i += 256) s += partials[i];
#pragma unroll
    for (int off = 32; off >= 1; off >>= 1)
        s += __shfl_xor(s, off, 64);

    __shared__ float sw[4];
    const int lane = threadIdx.x & 63;
    const int wave = threadIdx.x >> 6;
    if (lane == 0) sw[wave] = s;
    __syncthreads();
    if (threadIdx.x == 0) {
        out[0] = (sw[0] + sw[1] + sw[2] + sw[3]) * invN;
    }
}

extern "C" void kernel_launch(void* const* d_in, const int* in_sizes, int n_in,
                              void* d_out, int out_size, void* d_ws, size_t ws_size,
                              hipStream_t stream)
{
    const float* input  = (const float*)d_in[0];
    const int*   target = (const int*)d_in[1];
    const int N = in_sizes[1];
    const int C = in_sizes[0] / N;   // 1000

    float* partials = (float*)d_ws;  // NBLOCKS * 4 B = 8 KB scratch

    focal_rows<<<NBLOCKS, 256, 0, stream>>>(input, target, partials, N, C);
    reduce_partials<<<1, 256, 0, stream>>>(partials, NBLOCKS, (float*)d_out,
                                           1.0f / (float)N);
}